// Round 1
// baseline (1271.549 us; speedup 1.0000x reference)
//
#include <hip/hip_runtime.h>
#include <hip/hip_fp16.h>

#define B_  16
#define TA  2048
#define TV  1024
#define DD  512
#define NIT 20

static constexpr float EPSI  = 0.15f;
static constexpr float LOG2E = 1.4426950408889634f;

using f32x4 = __attribute__((ext_vector_type(4))) float;
using half8 = __attribute__((ext_vector_type(8))) _Float16;
using half4 = __attribute__((ext_vector_type(4))) _Float16;

__device__ inline float wave_max(float x) {
  #pragma unroll
  for (int m = 32; m; m >>= 1) x = fmaxf(x, __shfl_xor(x, m, 64));
  return x;
}
__device__ inline float wave_sum(float x) {
  #pragma unroll
  for (int m = 32; m; m >>= 1) x += __shfl_xor(x, m, 64);
  return x;
}

// ---------------- norms: inv L2 norm per row (audio rows then video rows) ---
__global__ __launch_bounds__(256) void norms_k(const float* __restrict__ audio,
                                               const float* __restrict__ video,
                                               float* __restrict__ inv_na,
                                               float* __restrict__ inv_nv) {
  int wid  = (blockIdx.x * blockDim.x + threadIdx.x) >> 6;
  int lane = threadIdx.x & 63;
  const float* src;
  float* dst;
  if (wid < B_ * TA) { src = audio + (size_t)wid * DD; dst = inv_na + wid; }
  else               { src = video + (size_t)(wid - B_ * TA) * DD; dst = inv_nv + (wid - B_ * TA); }
  const float4* s4 = (const float4*)src;
  float ss = 0.f;
  #pragma unroll
  for (int i = 0; i < 2; i++) {
    float4 v = s4[lane + i * 64];
    ss += v.x * v.x + v.y * v.y + v.z * v.z + v.w * v.w;
  }
  ss = wave_sum(ss);
  if (lane == 0) *dst = 1.0f / fmaxf(sqrtf(ss), 1e-12f);
}

// ---------------- v' init: v' = -c1 * lam_q * (1 - quality) ----------------
__global__ void vinit_k(const float* __restrict__ quality,
                        const float* __restrict__ lam_q,
                        float* __restrict__ Vp) {
  int i = blockIdx.x * blockDim.x + threadIdx.x;  // 0..B_*TV-1
  float c1 = LOG2E / EPSI;
  Vp[i] = -c1 * (*lam_q) * (1.0f - quality[i]);
}

// ---------------- cost GEMM: Ksmall2 = c1*(sim - 1 - lt*timedist) ----------
#define BM 128
#define BN 128
#define BK 64
#define LDH 72  // halves per LDS row (64 + 8 pad -> 144B stride, 2-way max)

__global__ __launch_bounds__(256) void cost_k(const float* __restrict__ audio,
                                              const float* __restrict__ video,
                                              const float* __restrict__ inv_na,
                                              const float* __restrict__ inv_nv,
                                              const float* __restrict__ lam_t,
                                              float* __restrict__ Kb) {
  __shared__ _Float16 As[BM * LDH];
  __shared__ _Float16 Bs[BN * LDH];
  int b  = blockIdx.z;
  int a0 = blockIdx.x * BM;
  int j0 = blockIdx.y * BN;
  int tid  = threadIdx.x;
  int lane = tid & 63;
  int wid  = tid >> 6;
  int wm = wid >> 1, wn = wid & 1;

  const float* Ab = audio + (size_t)b * TA * DD;
  const float* Vb = video + (size_t)b * TV * DD;

  f32x4 acc[4][4];
  #pragma unroll
  for (int i = 0; i < 4; i++)
    #pragma unroll
    for (int j = 0; j < 4; j++)
      #pragma unroll
      for (int r = 0; r < 4; r++) acc[i][j][r] = 0.f;

  int frow = tid >> 4;         // 0..15
  int fcol = (tid & 15) * 4;   // float idx 0..60
  int l16 = lane & 15, lq = lane >> 4;

  for (int kb = 0; kb < DD; kb += BK) {
    __syncthreads();
    // stage A tile: 128 rows x 64 d (f32 -> normalized f16)
    #pragma unroll
    for (int s = 0; s < 8; s++) {
      int r = frow + s * 16;
      float4 v = *(const float4*)&Ab[(size_t)(a0 + r) * DD + kb + fcol];
      float sc = inv_na[b * TA + a0 + r];
      half4 h = { (_Float16)(v.x * sc), (_Float16)(v.y * sc),
                  (_Float16)(v.z * sc), (_Float16)(v.w * sc) };
      *(half4*)&As[r * LDH + fcol] = h;
    }
    // stage B tile (video): 128 rows x 64 d
    #pragma unroll
    for (int s = 0; s < 8; s++) {
      int r = frow + s * 16;
      float4 v = *(const float4*)&Vb[(size_t)(j0 + r) * DD + kb + fcol];
      float sc = inv_nv[b * TV + j0 + r];
      half4 h = { (_Float16)(v.x * sc), (_Float16)(v.y * sc),
                  (_Float16)(v.z * sc), (_Float16)(v.w * sc) };
      *(half4*)&Bs[r * LDH + fcol] = h;
    }
    __syncthreads();
    #pragma unroll
    for (int ks = 0; ks < 2; ks++) {
      half8 af[4], bf[4];
      #pragma unroll
      for (int mf = 0; mf < 4; mf++)
        af[mf] = *(const half8*)&As[(wm * 64 + mf * 16 + l16) * LDH + ks * 32 + lq * 8];
      #pragma unroll
      for (int nf = 0; nf < 4; nf++)
        bf[nf] = *(const half8*)&Bs[(wn * 64 + nf * 16 + l16) * LDH + ks * 32 + lq * 8];
      #pragma unroll
      for (int mf = 0; mf < 4; mf++)
        #pragma unroll
        for (int nf = 0; nf < 4; nf++)
          acc[mf][nf] = __builtin_amdgcn_mfma_f32_16x16x32_f16(af[mf], bf[nf], acc[mf][nf], 0, 0, 0);
    }
  }

  float lt = *lam_t;
  float c1 = LOG2E / EPSI;
  #pragma unroll
  for (int mf = 0; mf < 4; mf++)
    #pragma unroll
    for (int nf = 0; nf < 4; nf++)
      #pragma unroll
      for (int r = 0; r < 4; r++) {
        int a = a0 + wm * 64 + mf * 16 + lq * 4 + r;
        int j = j0 + wn * 64 + nf * 16 + l16;
        float sim = acc[mf][nf][r];
        float td = fabsf((float)a * (1.0f / TA) - (float)j * (1.0f / TV));
        Kb[((size_t)b * TA + a) * TV + j] = c1 * (sim - 1.0f - lt * td);
      }
}

// ---------------- u-update: one wave per (b,a) row -------------------------
__global__ __launch_bounds__(256) void u_k(const float* __restrict__ Kb,
                                           const float* __restrict__ Vp,
                                           float* __restrict__ U) {
  int wid  = (blockIdx.x * blockDim.x + threadIdx.x) >> 6;  // 0..B_*TA-1
  int lane = threadIdx.x & 63;
  int b = wid >> 11;
  const float* row = Kb + (size_t)wid * TV;
  const float* vp  = Vp + b * TV;
  float x[16];
  #pragma unroll
  for (int q = 0; q < 4; q++) {
    float4 kv = *(const float4*)&row[q * 256 + lane * 4];
    float4 vv = *(const float4*)&vp[q * 256 + lane * 4];
    x[q * 4 + 0] = kv.x + vv.x; x[q * 4 + 1] = kv.y + vv.y;
    x[q * 4 + 2] = kv.z + vv.z; x[q * 4 + 3] = kv.w + vv.w;
  }
  float m = -3.0e38f;
  #pragma unroll
  for (int i = 0; i < 16; i++) m = fmaxf(m, x[i]);
  m = wave_max(m);
  float s = 0.f;
  #pragma unroll
  for (int i = 0; i < 16; i++) s += exp2f(x[i] - m);
  s = wave_sum(s);
  if (lane == 0) U[wid] = -(m + log2f(s));
}

// ---------------- v partial: columns, a split into 8 chunks of 256 ---------
__global__ __launch_bounds__(256) void vpart_k(const float* __restrict__ Kb,
                                               const float* __restrict__ U,
                                               float* __restrict__ pm,
                                               float* __restrict__ ps) {
  int j = blockIdx.x * 256 + threadIdx.x;   // 0..1023
  int c = blockIdx.y;                       // 0..7
  int b = blockIdx.z;                       // 0..15
  const float* Kbase = Kb + ((size_t)b * TA + c * 256) * TV + j;
  const float* Ub    = U + b * TA + c * 256;
  float m = -3.0e38f, s = 0.f;
  #pragma unroll 4
  for (int a = 0; a < 256; a++) {
    float x  = Kbase[(size_t)a * TV] + Ub[a];
    float nm = fmaxf(m, x);
    s = s * exp2f(m - nm) + exp2f(x - nm);
    m = nm;
  }
  size_t o = ((size_t)b * 8 + c) * TV + j;
  pm[o] = m; ps[o] = s;
}

// ---------------- v combine ------------------------------------------------
__global__ void vcomb_k(const float* __restrict__ pm,
                        const float* __restrict__ ps,
                        float* __restrict__ Vp) {
  int i = blockIdx.x * blockDim.x + threadIdx.x;  // 0..B_*TV-1
  int b = i >> 10, j = i & 1023;
  float M = -3.0e38f;
  #pragma unroll
  for (int c = 0; c < 8; c++) M = fmaxf(M, pm[((size_t)b * 8 + c) * TV + j]);
  float S = 0.f;
  #pragma unroll
  for (int c = 0; c < 8; c++) {
    size_t o = ((size_t)b * 8 + c) * TV + j;
    S += ps[o] * exp2f(pm[o] - M);
  }
  Vp[i] = -(M + log2f(S));
}

// ---------------- final: transport = exp2(K+u+v') / (rowsum + 1e-8) --------
__global__ __launch_bounds__(256) void final_k(float* __restrict__ Kb,
                                               const float* __restrict__ U,
                                               const float* __restrict__ Vp) {
  int wid  = (blockIdx.x * blockDim.x + threadIdx.x) >> 6;
  int lane = threadIdx.x & 63;
  int b = wid >> 11;
  float* row = Kb + (size_t)wid * TV;
  const float* vp = Vp + b * TV;
  float u = U[wid];
  float t[16];
  float s = 0.f;
  #pragma unroll
  for (int q = 0; q < 4; q++) {
    float4 kv = *(const float4*)&row[q * 256 + lane * 4];
    float4 vv = *(const float4*)&vp[q * 256 + lane * 4];
    t[q * 4 + 0] = exp2f(kv.x + vv.x + u);
    t[q * 4 + 1] = exp2f(kv.y + vv.y + u);
    t[q * 4 + 2] = exp2f(kv.z + vv.z + u);
    t[q * 4 + 3] = exp2f(kv.w + vv.w + u);
    s += t[q * 4 + 0] + t[q * 4 + 1] + t[q * 4 + 2] + t[q * 4 + 3];
  }
  s = wave_sum(s);
  float inv = 1.0f / (s + 1e-8f);
  #pragma unroll
  for (int q = 0; q < 4; q++) {
    float4 o;
    o.x = t[q * 4 + 0] * inv; o.y = t[q * 4 + 1] * inv;
    o.z = t[q * 4 + 2] * inv; o.w = t[q * 4 + 3] * inv;
    *(float4*)&row[q * 256 + lane * 4] = o;
  }
}

extern "C" void kernel_launch(void* const* d_in, const int* in_sizes, int n_in,
                              void* d_out, int out_size, void* d_ws, size_t ws_size,
                              hipStream_t stream) {
  const float* audio   = (const float*)d_in[0];
  const float* video   = (const float*)d_in[1];
  const float* quality = (const float*)d_in[2];
  const float* lam_t   = (const float*)d_in[3];
  const float* lam_q   = (const float*)d_in[4];

  float* Kb = (float*)d_out;       // K (log2-domain, quality-factored) lives in d_out
  float* ws = (float*)d_ws;
  float* inv_na = ws;              // 32768
  float* inv_nv = ws + 32768;      // 16384
  float* U      = ws + 49152;      // 32768
  float* Vp     = ws + 81920;      // 16384
  float* pm     = ws + 98304;      // 16*8*1024
  float* ps     = ws + 229376;     // 16*8*1024

  norms_k<<<12288, 256, 0, stream>>>(audio, video, inv_na, inv_nv);
  vinit_k<<<64, 256, 0, stream>>>(quality, lam_q, Vp);
  cost_k<<<dim3(16, 8, 16), 256, 0, stream>>>(audio, video, inv_na, inv_nv, lam_t, Kb);
  for (int it = 0; it < NIT; it++) {
    u_k<<<8192, 256, 0, stream>>>(Kb, Vp, U);
    vpart_k<<<dim3(4, 8, 16), 256, 0, stream>>>(Kb, U, pm, ps);
    vcomb_k<<<64, 256, 0, stream>>>(pm, ps, Vp);
  }
  final_k<<<8192, 256, 0, stream>>>(Kb, U, Vp);
}

// Round 2
// 1051.099 us; speedup vs baseline: 1.2097x; 1.2097x over previous
//
#include <hip/hip_runtime.h>
#include <hip/hip_fp16.h>

#define B_  16
#define TA  2048
#define TV  1024
#define DD  512
#define NIT 20

static constexpr float EPSI  = 0.15f;
static constexpr float LOG2E = 1.4426950408889634f;

using f32x4 = __attribute__((ext_vector_type(4))) float;
using half8 = __attribute__((ext_vector_type(8))) _Float16;
using half4 = __attribute__((ext_vector_type(4))) _Float16;

__device__ inline float wave_max(float x) {
  #pragma unroll
  for (int m = 32; m; m >>= 1) x = fmaxf(x, __shfl_xor(x, m, 64));
  return x;
}
__device__ inline float wave_sum(float x) {
  #pragma unroll
  for (int m = 32; m; m >>= 1) x += __shfl_xor(x, m, 64);
  return x;
}

// ---------------- norms: inv L2 norm per row (audio rows then video rows) ---
__global__ __launch_bounds__(256) void norms_k(const float* __restrict__ audio,
                                               const float* __restrict__ video,
                                               float* __restrict__ inv_na,
                                               float* __restrict__ inv_nv) {
  int wid  = (blockIdx.x * blockDim.x + threadIdx.x) >> 6;
  int lane = threadIdx.x & 63;
  const float* src;
  float* dst;
  if (wid < B_ * TA) { src = audio + (size_t)wid * DD; dst = inv_na + wid; }
  else               { src = video + (size_t)(wid - B_ * TA) * DD; dst = inv_nv + (wid - B_ * TA); }
  const float4* s4 = (const float4*)src;
  float ss = 0.f;
  #pragma unroll
  for (int i = 0; i < 2; i++) {
    float4 v = s4[lane + i * 64];
    ss += v.x * v.x + v.y * v.y + v.z * v.z + v.w * v.w;
  }
  ss = wave_sum(ss);
  if (lane == 0) *dst = 1.0f / fmaxf(sqrtf(ss), 1e-12f);
}

// ---------------- v' init: v' = -c1 * lam_q * (1 - quality) ----------------
__global__ void vinit_k(const float* __restrict__ quality,
                        const float* __restrict__ lam_q,
                        float* __restrict__ Vp) {
  int i = blockIdx.x * blockDim.x + threadIdx.x;  // 0..B_*TV-1
  float c1 = LOG2E / EPSI;
  Vp[i] = -c1 * (*lam_q) * (1.0f - quality[i]);
}

// ---------------- cost GEMM: Ksmall2 = c1*(sim - 1 - lt*timedist) ----------
#define BM 128
#define BN 128
#define BK 64
#define LDH 72  // halves per LDS row

__global__ __launch_bounds__(256) void cost_k(const float* __restrict__ audio,
                                              const float* __restrict__ video,
                                              const float* __restrict__ inv_na,
                                              const float* __restrict__ inv_nv,
                                              const float* __restrict__ lam_t,
                                              float* __restrict__ Kb) {
  __shared__ _Float16 As[BM * LDH];
  __shared__ _Float16 Bs[BN * LDH];
  int b  = blockIdx.z;
  int a0 = blockIdx.x * BM;
  int j0 = blockIdx.y * BN;
  int tid  = threadIdx.x;
  int lane = tid & 63;
  int wid  = tid >> 6;
  int wm = wid >> 1, wn = wid & 1;

  const float* Ab = audio + (size_t)b * TA * DD;
  const float* Vb = video + (size_t)b * TV * DD;

  f32x4 acc[4][4];
  #pragma unroll
  for (int i = 0; i < 4; i++)
    #pragma unroll
    for (int j = 0; j < 4; j++)
      #pragma unroll
      for (int r = 0; r < 4; r++) acc[i][j][r] = 0.f;

  int frow = tid >> 4;
  int fcol = (tid & 15) * 4;
  int l16 = lane & 15, lq = lane >> 4;

  for (int kb = 0; kb < DD; kb += BK) {
    __syncthreads();
    #pragma unroll
    for (int s = 0; s < 8; s++) {
      int r = frow + s * 16;
      float4 v = *(const float4*)&Ab[(size_t)(a0 + r) * DD + kb + fcol];
      float sc = inv_na[b * TA + a0 + r];
      half4 h = { (_Float16)(v.x * sc), (_Float16)(v.y * sc),
                  (_Float16)(v.z * sc), (_Float16)(v.w * sc) };
      *(half4*)&As[r * LDH + fcol] = h;
    }
    #pragma unroll
    for (int s = 0; s < 8; s++) {
      int r = frow + s * 16;
      float4 v = *(const float4*)&Vb[(size_t)(j0 + r) * DD + kb + fcol];
      float sc = inv_nv[b * TV + j0 + r];
      half4 h = { (_Float16)(v.x * sc), (_Float16)(v.y * sc),
                  (_Float16)(v.z * sc), (_Float16)(v.w * sc) };
      *(half4*)&Bs[r * LDH + fcol] = h;
    }
    __syncthreads();
    #pragma unroll
    for (int ks = 0; ks < 2; ks++) {
      half8 af[4], bf[4];
      #pragma unroll
      for (int mf = 0; mf < 4; mf++)
        af[mf] = *(const half8*)&As[(wm * 64 + mf * 16 + l16) * LDH + ks * 32 + lq * 8];
      #pragma unroll
      for (int nf = 0; nf < 4; nf++)
        bf[nf] = *(const half8*)&Bs[(wn * 64 + nf * 16 + l16) * LDH + ks * 32 + lq * 8];
      #pragma unroll
      for (int mf = 0; mf < 4; mf++)
        #pragma unroll
        for (int nf = 0; nf < 4; nf++)
          acc[mf][nf] = __builtin_amdgcn_mfma_f32_16x16x32_f16(af[mf], bf[nf], acc[mf][nf], 0, 0, 0);
    }
  }

  float lt = *lam_t;
  float c1 = LOG2E / EPSI;
  #pragma unroll
  for (int mf = 0; mf < 4; mf++)
    #pragma unroll
    for (int nf = 0; nf < 4; nf++)
      #pragma unroll
      for (int r = 0; r < 4; r++) {
        int a = a0 + wm * 64 + mf * 16 + lq * 4 + r;
        int j = j0 + wn * 64 + nf * 16 + l16;
        float sim = acc[mf][nf][r];
        float td = fabsf((float)a * (1.0f / TA) - (float)j * (1.0f / TV));
        Kb[((size_t)b * TA + a) * TV + j] = c1 * (sim - 1.0f - lt * td);
      }
}

// ---------------- FUSED iteration: u-update + column partials in one scan --
// block = 512 thr (8 waves); wave owns 8 rows; block covers 64 rows.
// grid.x = B_*TA/64 = 512
__global__ __launch_bounds__(512) void fused_k(const float* __restrict__ Kb,
                                               const float* __restrict__ Vp,
                                               float* __restrict__ U,
                                               float* __restrict__ pm,
                                               float* __restrict__ ps) {
  __shared__ float lm[8][1024];
  __shared__ float ls[8][1024];
  int tid = threadIdx.x, lane = tid & 63, wid = tid >> 6;
  int gw   = blockIdx.x * 8 + wid;
  int row0 = gw * 8;               // global row (b*TA + a)
  int b    = row0 >> 11;
  const float* vp = Vp + b * TV;

  float vpl[16];
  #pragma unroll
  for (int q = 0; q < 4; q++) {
    float4 v = *(const float4*)&vp[q * 256 + lane * 4];
    vpl[q*4+0] = v.x; vpl[q*4+1] = v.y; vpl[q*4+2] = v.z; vpl[q*4+3] = v.w;
  }
  float mc[16], sc[16];
  #pragma unroll
  for (int i = 0; i < 16; i++) { mc[i] = -3.0e38f; sc[i] = 0.f; }

  #pragma unroll 2
  for (int r = 0; r < 8; r++) {
    const float* row = Kb + (size_t)(row0 + r) * TV;
    float x[16];
    #pragma unroll
    for (int q = 0; q < 4; q++) {
      float4 kv = *(const float4*)&row[q * 256 + lane * 4];
      x[q*4+0] = kv.x + vpl[q*4+0]; x[q*4+1] = kv.y + vpl[q*4+1];
      x[q*4+2] = kv.z + vpl[q*4+2]; x[q*4+3] = kv.w + vpl[q*4+3];
    }
    float m = x[0];
    #pragma unroll
    for (int i = 1; i < 16; i++) m = fmaxf(m, x[i]);
    m = wave_max(m);
    float s = 0.f;
    #pragma unroll
    for (int i = 0; i < 16; i++) s += exp2f(x[i] - m);
    s = wave_sum(s);
    float u = -(m + log2f(s));
    if (lane == 0) U[row0 + r] = u;
    #pragma unroll
    for (int i = 0; i < 16; i++) {
      float y  = x[i] - vpl[i] + u;       // K + u
      float nm = fmaxf(mc[i], y);
      sc[i] = sc[i] * exp2f(mc[i] - nm) + exp2f(y - nm);
      mc[i] = nm;
    }
  }

  // merge the 8 waves' column partials in LDS
  #pragma unroll
  for (int q = 0; q < 4; q++) {
    int col = q * 256 + lane * 4;
    *(float4*)&lm[wid][col] = make_float4(mc[q*4+0], mc[q*4+1], mc[q*4+2], mc[q*4+3]);
    *(float4*)&ls[wid][col] = make_float4(sc[q*4+0], sc[q*4+1], sc[q*4+2], sc[q*4+3]);
  }
  __syncthreads();
  #pragma unroll
  for (int k = 0; k < 2; k++) {
    int col = tid + k * 512;
    float M = lm[0][col];
    #pragma unroll
    for (int w = 1; w < 8; w++) M = fmaxf(M, lm[w][col]);
    float S = 0.f;
    #pragma unroll
    for (int w = 0; w < 8; w++) S += ls[w][col] * exp2f(lm[w][col] - M);
    pm[(size_t)blockIdx.x * 1024 + col] = M;
    ps[(size_t)blockIdx.x * 1024 + col] = S;
  }
}

// ---------------- combine 32 chunks/batch -> new Vp ------------------------
__global__ void vcomb2_k(const float* __restrict__ pm,
                         const float* __restrict__ ps,
                         float* __restrict__ Vp) {
  int i = blockIdx.x * blockDim.x + threadIdx.x;  // 0..B_*TV-1
  int b = i >> 10, j = i & 1023;
  float M = -3.0e38f;
  #pragma unroll
  for (int c = 0; c < 32; c++) M = fmaxf(M, pm[(size_t)(b * 32 + c) * 1024 + j]);
  float S = 0.f;
  #pragma unroll
  for (int c = 0; c < 32; c++) {
    size_t o = (size_t)(b * 32 + c) * 1024 + j;
    S += ps[o] * exp2f(pm[o] - M);
  }
  Vp[i] = -(M + log2f(S));
}

// ---------------- fallback loop kernels (small-ws path) --------------------
__global__ __launch_bounds__(256) void u_k(const float* __restrict__ Kb,
                                           const float* __restrict__ Vp,
                                           float* __restrict__ U) {
  int wid  = (blockIdx.x * blockDim.x + threadIdx.x) >> 6;
  int lane = threadIdx.x & 63;
  int b = wid >> 11;
  const float* row = Kb + (size_t)wid * TV;
  const float* vp  = Vp + b * TV;
  float x[16];
  #pragma unroll
  for (int q = 0; q < 4; q++) {
    float4 kv = *(const float4*)&row[q * 256 + lane * 4];
    float4 vv = *(const float4*)&vp[q * 256 + lane * 4];
    x[q*4+0] = kv.x + vv.x; x[q*4+1] = kv.y + vv.y;
    x[q*4+2] = kv.z + vv.z; x[q*4+3] = kv.w + vv.w;
  }
  float m = -3.0e38f;
  #pragma unroll
  for (int i = 0; i < 16; i++) m = fmaxf(m, x[i]);
  m = wave_max(m);
  float s = 0.f;
  #pragma unroll
  for (int i = 0; i < 16; i++) s += exp2f(x[i] - m);
  s = wave_sum(s);
  if (lane == 0) U[wid] = -(m + log2f(s));
}

__global__ __launch_bounds__(256) void vpart_k(const float* __restrict__ Kb,
                                               const float* __restrict__ U,
                                               float* __restrict__ pm,
                                               float* __restrict__ ps) {
  int j = blockIdx.x * 256 + threadIdx.x;
  int c = blockIdx.y;
  int b = blockIdx.z;
  const float* Kbase = Kb + ((size_t)b * TA + c * 256) * TV + j;
  const float* Ub    = U + b * TA + c * 256;
  float m = -3.0e38f, s = 0.f;
  #pragma unroll 4
  for (int a = 0; a < 256; a++) {
    float x  = Kbase[(size_t)a * TV] + Ub[a];
    float nm = fmaxf(m, x);
    s = s * exp2f(m - nm) + exp2f(x - nm);
    m = nm;
  }
  size_t o = ((size_t)b * 8 + c) * TV + j;
  pm[o] = m; ps[o] = s;
}

__global__ void vcomb_k(const float* __restrict__ pm,
                        const float* __restrict__ ps,
                        float* __restrict__ Vp) {
  int i = blockIdx.x * blockDim.x + threadIdx.x;
  int b = i >> 10, j = i & 1023;
  float M = -3.0e38f;
  #pragma unroll
  for (int c = 0; c < 8; c++) M = fmaxf(M, pm[((size_t)b * 8 + c) * TV + j]);
  float S = 0.f;
  #pragma unroll
  for (int c = 0; c < 8; c++) {
    size_t o = ((size_t)b * 8 + c) * TV + j;
    S += ps[o] * exp2f(pm[o] - M);
  }
  Vp[i] = -(M + log2f(S));
}

// ---------------- final: transport = exp2(K+u+v') / (rowsum + 1e-8) --------
__global__ __launch_bounds__(256) void final_k(float* __restrict__ Kb,
                                               const float* __restrict__ U,
                                               const float* __restrict__ Vp) {
  int wid  = (blockIdx.x * blockDim.x + threadIdx.x) >> 6;
  int lane = threadIdx.x & 63;
  int b = wid >> 11;
  float* row = Kb + (size_t)wid * TV;
  const float* vp = Vp + b * TV;
  float u = U[wid];
  float t[16];
  float s = 0.f;
  #pragma unroll
  for (int q = 0; q < 4; q++) {
    float4 kv = *(const float4*)&row[q * 256 + lane * 4];
    float4 vv = *(const float4*)&vp[q * 256 + lane * 4];
    t[q*4+0] = exp2f(kv.x + vv.x + u);
    t[q*4+1] = exp2f(kv.y + vv.y + u);
    t[q*4+2] = exp2f(kv.z + vv.z + u);
    t[q*4+3] = exp2f(kv.w + vv.w + u);
    s += t[q*4+0] + t[q*4+1] + t[q*4+2] + t[q*4+3];
  }
  s = wave_sum(s);
  float inv = 1.0f / (s + 1e-8f);
  #pragma unroll
  for (int q = 0; q < 4; q++) {
    float4 o;
    o.x = t[q*4+0] * inv; o.y = t[q*4+1] * inv;
    o.z = t[q*4+2] * inv; o.w = t[q*4+3] * inv;
    *(float4*)&row[q * 256 + lane * 4] = o;
  }
}

extern "C" void kernel_launch(void* const* d_in, const int* in_sizes, int n_in,
                              void* d_out, int out_size, void* d_ws, size_t ws_size,
                              hipStream_t stream) {
  const float* audio   = (const float*)d_in[0];
  const float* video   = (const float*)d_in[1];
  const float* quality = (const float*)d_in[2];
  const float* lam_t   = (const float*)d_in[3];
  const float* lam_q   = (const float*)d_in[4];

  float* Kb = (float*)d_out;
  float* ws = (float*)d_ws;
  float* inv_na = ws;                    // 32768
  float* inv_nv = ws + 32768;            // 16384
  float* U      = ws + 49152;            // 32768
  float* Vp     = ws + 81920;            // 16384
  float* pm     = ws + 98304;            // up to 512*1024
  float* ps     = ws + 98304 + 524288;   // up to 512*1024

  norms_k<<<12288, 256, 0, stream>>>(audio, video, inv_na, inv_nv);
  vinit_k<<<64, 256, 0, stream>>>(quality, lam_q, Vp);
  cost_k<<<dim3(16, 8, 16), 256, 0, stream>>>(audio, video, inv_na, inv_nv, lam_t, Kb);

  size_t need_fused = (size_t)(98304 + 2 * 524288) * sizeof(float);
  if (ws_size >= need_fused) {
    for (int it = 0; it < NIT; it++) {
      fused_k<<<512, 512, 0, stream>>>(Kb, Vp, U, pm, ps);
      vcomb2_k<<<64, 256, 0, stream>>>(pm, ps, Vp);
    }
  } else {
    for (int it = 0; it < NIT; it++) {
      u_k<<<8192, 256, 0, stream>>>(Kb, Vp, U);
      vpart_k<<<dim3(4, 8, 16), 256, 0, stream>>>(Kb, U, pm, ps);
      vcomb_k<<<64, 256, 0, stream>>>(pm, ps, Vp);
    }
  }
  final_k<<<8192, 256, 0, stream>>>(Kb, U, Vp);
}

// Round 3
// 486.112 us; speedup vs baseline: 2.6158x; 2.1623x over previous
//
#include <hip/hip_runtime.h>
#include <hip/hip_fp16.h>

#define B_  16
#define TA  2048
#define TV  1024
#define DD  512
#define NIT 20

static constexpr float EPSI  = 0.15f;
static constexpr float LOG2E = 1.4426950408889634f;

using f32x4 = __attribute__((ext_vector_type(4))) float;
using half8 = __attribute__((ext_vector_type(8))) _Float16;
using half4 = __attribute__((ext_vector_type(4))) _Float16;

__device__ inline float wave_sum(float x) {
  #pragma unroll
  for (int m = 32; m; m >>= 1) x += __shfl_xor(x, m, 64);
  return x;
}

// ---------------- norms: inv L2 norm per row (audio rows then video rows) ---
__global__ __launch_bounds__(256) void norms_k(const float* __restrict__ audio,
                                               const float* __restrict__ video,
                                               float* __restrict__ inv_na,
                                               float* __restrict__ inv_nv) {
  int wid  = (blockIdx.x * blockDim.x + threadIdx.x) >> 6;
  int lane = threadIdx.x & 63;
  const float* src;
  float* dst;
  if (wid < B_ * TA) { src = audio + (size_t)wid * DD; dst = inv_na + wid; }
  else               { src = video + (size_t)(wid - B_ * TA) * DD; dst = inv_nv + (wid - B_ * TA); }
  const float4* s4 = (const float4*)src;
  float ss = 0.f;
  #pragma unroll
  for (int i = 0; i < 2; i++) {
    float4 v = s4[lane + i * 64];
    ss += v.x * v.x + v.y * v.y + v.z * v.z + v.w * v.w;
  }
  ss = wave_sum(ss);
  if (lane == 0) *dst = 1.0f / fmaxf(sqrtf(ss), 1e-12f);
}

// ---------------- v' init: v' = -c1 * lam_q * (1 - quality) ----------------
__global__ void vinit_k(const float* __restrict__ quality,
                        const float* __restrict__ lam_q,
                        float* __restrict__ Vp) {
  int i = blockIdx.x * blockDim.x + threadIdx.x;  // 0..B_*TV-1
  float c1 = LOG2E / EPSI;
  Vp[i] = -c1 * (*lam_q) * (1.0f - quality[i]);
}

// ---------------- cost GEMM: Ksmall2 = c1*(sim - 1 - lt*timedist) ----------
#define BM 128
#define BN 128
#define BK 64
#define LDH 72

template<bool F16>
__global__ __launch_bounds__(256) void cost_k(const float* __restrict__ audio,
                                              const float* __restrict__ video,
                                              const float* __restrict__ inv_na,
                                              const float* __restrict__ inv_nv,
                                              const float* __restrict__ lam_t,
                                              float* __restrict__ Kb,
                                              _Float16* __restrict__ Kh) {
  __shared__ _Float16 As[BM * LDH];
  __shared__ _Float16 Bs[BN * LDH];
  int b  = blockIdx.z;
  int a0 = blockIdx.x * BM;
  int j0 = blockIdx.y * BN;
  int tid  = threadIdx.x;
  int lane = tid & 63;
  int wid  = tid >> 6;
  int wm = wid >> 1, wn = wid & 1;

  const float* Ab = audio + (size_t)b * TA * DD;
  const float* Vb = video + (size_t)b * TV * DD;

  f32x4 acc[4][4];
  #pragma unroll
  for (int i = 0; i < 4; i++)
    #pragma unroll
    for (int j = 0; j < 4; j++)
      #pragma unroll
      for (int r = 0; r < 4; r++) acc[i][j][r] = 0.f;

  int frow = tid >> 4;
  int fcol = (tid & 15) * 4;
  int l16 = lane & 15, lq = lane >> 4;

  for (int kb = 0; kb < DD; kb += BK) {
    __syncthreads();
    #pragma unroll
    for (int s = 0; s < 8; s++) {
      int r = frow + s * 16;
      float4 v = *(const float4*)&Ab[(size_t)(a0 + r) * DD + kb + fcol];
      float sc = inv_na[b * TA + a0 + r];
      half4 h = { (_Float16)(v.x * sc), (_Float16)(v.y * sc),
                  (_Float16)(v.z * sc), (_Float16)(v.w * sc) };
      *(half4*)&As[r * LDH + fcol] = h;
    }
    #pragma unroll
    for (int s = 0; s < 8; s++) {
      int r = frow + s * 16;
      float4 v = *(const float4*)&Vb[(size_t)(j0 + r) * DD + kb + fcol];
      float sc = inv_nv[b * TV + j0 + r];
      half4 h = { (_Float16)(v.x * sc), (_Float16)(v.y * sc),
                  (_Float16)(v.z * sc), (_Float16)(v.w * sc) };
      *(half4*)&Bs[r * LDH + fcol] = h;
    }
    __syncthreads();
    #pragma unroll
    for (int ks = 0; ks < 2; ks++) {
      half8 af[4], bf[4];
      #pragma unroll
      for (int mf = 0; mf < 4; mf++)
        af[mf] = *(const half8*)&As[(wm * 64 + mf * 16 + l16) * LDH + ks * 32 + lq * 8];
      #pragma unroll
      for (int nf = 0; nf < 4; nf++)
        bf[nf] = *(const half8*)&Bs[(wn * 64 + nf * 16 + l16) * LDH + ks * 32 + lq * 8];
      #pragma unroll
      for (int mf = 0; mf < 4; mf++)
        #pragma unroll
        for (int nf = 0; nf < 4; nf++)
          acc[mf][nf] = __builtin_amdgcn_mfma_f32_16x16x32_f16(af[mf], bf[nf], acc[mf][nf], 0, 0, 0);
    }
  }

  float lt = *lam_t;
  float c1 = LOG2E / EPSI;
  #pragma unroll
  for (int mf = 0; mf < 4; mf++)
    #pragma unroll
    for (int nf = 0; nf < 4; nf++)
      #pragma unroll
      for (int r = 0; r < 4; r++) {
        int a = a0 + wm * 64 + mf * 16 + lq * 4 + r;
        int j = j0 + wn * 64 + nf * 16 + l16;
        float sim = acc[mf][nf][r];
        float td = fabsf((float)a * (1.0f / TA) - (float)j * (1.0f / TV));
        float val = c1 * (sim - 1.0f - lt * td);
        size_t o = ((size_t)b * TA + a) * TV + j;
        if constexpr (F16) Kh[o] = (_Float16)val;
        else               Kb[o] = val;
      }
}

// ---------------- iteration scan (f16 K): rowsum + colsum of row-softmax ---
// block 512 thr (8 waves), wave owns 8 rows, block = 64 rows, grid 512.
__global__ __launch_bounds__(512) void iter16_k(const _Float16* __restrict__ Kh,
                                                const float* __restrict__ Vp,
                                                float* __restrict__ pc) {
  __shared__ float lc[8][1024];
  int tid = threadIdx.x, lane = tid & 63, wid = tid >> 6;
  int row0 = (blockIdx.x * 8 + wid) * 8;
  int b = row0 >> 11;
  const float* vp = Vp + b * TV + lane * 8;
  float vpl[16];
  *(float4*)&vpl[0]  = *(const float4*)&vp[0];
  *(float4*)&vpl[4]  = *(const float4*)&vp[4];
  *(float4*)&vpl[8]  = *(const float4*)&vp[512];
  *(float4*)&vpl[12] = *(const float4*)&vp[516];
  float C[16];
  #pragma unroll
  for (int i = 0; i < 16; i++) C[i] = 0.f;

  #pragma unroll 2
  for (int r = 0; r < 8; r++) {
    const _Float16* row = Kh + (size_t)(row0 + r) * TV + lane * 8;
    half8 h0 = *(const half8*)&row[0];
    half8 h1 = *(const half8*)&row[512];
    float e[16];
    float s = 0.f;
    #pragma unroll
    for (int i = 0; i < 8; i++) { e[i] = exp2f((float)h0[i] + vpl[i]); s += e[i]; }
    #pragma unroll
    for (int i = 0; i < 8; i++) { e[8 + i] = exp2f((float)h1[i] + vpl[8 + i]); s += e[8 + i]; }
    s = wave_sum(s);
    float w = 1.0f / s;                    // exp2(u_row); u never materialized
    #pragma unroll
    for (int i = 0; i < 16; i++) C[i] = fmaf(e[i], w, C[i]);
  }

  *(float4*)&lc[wid][lane * 8]       = make_float4(C[0], C[1], C[2], C[3]);
  *(float4*)&lc[wid][lane * 8 + 4]   = make_float4(C[4], C[5], C[6], C[7]);
  *(float4*)&lc[wid][512 + lane * 8]     = make_float4(C[8], C[9], C[10], C[11]);
  *(float4*)&lc[wid][512 + lane * 8 + 4] = make_float4(C[12], C[13], C[14], C[15]);
  __syncthreads();
  #pragma unroll
  for (int k = 0; k < 2; k++) {
    int col = tid + k * 512;
    float S = 0.f;
    #pragma unroll
    for (int w = 0; w < 8; w++) S += lc[w][col];
    pc[(size_t)blockIdx.x * 1024 + col] = S;
  }
}

// ---------------- iteration scan (f32 K fallback) --------------------------
__global__ __launch_bounds__(512) void iter32_k(const float* __restrict__ Kb,
                                                const float* __restrict__ Vp,
                                                float* __restrict__ pc) {
  __shared__ float lc[8][1024];
  int tid = threadIdx.x, lane = tid & 63, wid = tid >> 6;
  int row0 = (blockIdx.x * 8 + wid) * 8;
  int b = row0 >> 11;
  const float* vp = Vp + b * TV;
  float vpl[16];
  #pragma unroll
  for (int q = 0; q < 4; q++)
    *(float4*)&vpl[q * 4] = *(const float4*)&vp[q * 256 + lane * 4];
  float C[16];
  #pragma unroll
  for (int i = 0; i < 16; i++) C[i] = 0.f;

  #pragma unroll 2
  for (int r = 0; r < 8; r++) {
    const float* row = Kb + (size_t)(row0 + r) * TV;
    float e[16];
    float s = 0.f;
    #pragma unroll
    for (int q = 0; q < 4; q++) {
      float4 kv = *(const float4*)&row[q * 256 + lane * 4];
      e[q*4+0] = exp2f(kv.x + vpl[q*4+0]);
      e[q*4+1] = exp2f(kv.y + vpl[q*4+1]);
      e[q*4+2] = exp2f(kv.z + vpl[q*4+2]);
      e[q*4+3] = exp2f(kv.w + vpl[q*4+3]);
      s += e[q*4+0] + e[q*4+1] + e[q*4+2] + e[q*4+3];
    }
    s = wave_sum(s);
    float w = 1.0f / s;
    #pragma unroll
    for (int i = 0; i < 16; i++) C[i] = fmaf(e[i], w, C[i]);
  }

  #pragma unroll
  for (int q = 0; q < 4; q++)
    *(float4*)&lc[wid][q * 256 + lane * 4] =
        make_float4(C[q*4+0], C[q*4+1], C[q*4+2], C[q*4+3]);
  __syncthreads();
  #pragma unroll
  for (int k = 0; k < 2; k++) {
    int col = tid + k * 512;
    float S = 0.f;
    #pragma unroll
    for (int w = 0; w < 8; w++) S += lc[w][col];
    pc[(size_t)blockIdx.x * 1024 + col] = S;
  }
}

// ---------------- v' update: Vp -= log2(sum of partial colsums) ------------
__global__ void vcomb_k(const float* __restrict__ pc, float* __restrict__ Vp) {
  int i = blockIdx.x * blockDim.x + threadIdx.x;  // 0..B_*TV-1
  int b = i >> 10, j = i & 1023;
  const float* p = pc + (size_t)(b * 32) * 1024 + j;
  float S = 0.f;
  #pragma unroll
  for (int c = 0; c < 32; c++) S += p[c * 1024];
  Vp[i] -= log2f(S);
}

// ---------------- final: transport = row-softmax(K + v'_20) ----------------
__global__ __launch_bounds__(256) void final16_k(const _Float16* __restrict__ Kh,
                                                 const float* __restrict__ Vp,
                                                 float* __restrict__ out) {
  int gw   = (blockIdx.x * blockDim.x + threadIdx.x) >> 6;  // row
  int lane = threadIdx.x & 63;
  int b = gw >> 11;
  const float* vp = Vp + b * TV + lane * 8;
  float vpl[16];
  *(float4*)&vpl[0]  = *(const float4*)&vp[0];
  *(float4*)&vpl[4]  = *(const float4*)&vp[4];
  *(float4*)&vpl[8]  = *(const float4*)&vp[512];
  *(float4*)&vpl[12] = *(const float4*)&vp[516];
  const _Float16* row = Kh + (size_t)gw * TV + lane * 8;
  half8 h0 = *(const half8*)&row[0];
  half8 h1 = *(const half8*)&row[512];
  float e[16];
  float s = 0.f;
  #pragma unroll
  for (int i = 0; i < 8; i++) { e[i] = exp2f((float)h0[i] + vpl[i]); s += e[i]; }
  #pragma unroll
  for (int i = 0; i < 8; i++) { e[8 + i] = exp2f((float)h1[i] + vpl[8 + i]); s += e[8 + i]; }
  s = wave_sum(s);
  float inv = 1.0f / s;
  float* o = out + (size_t)gw * TV + lane * 8;
  *(float4*)&o[0]   = make_float4(e[0] * inv, e[1] * inv, e[2] * inv, e[3] * inv);
  *(float4*)&o[4]   = make_float4(e[4] * inv, e[5] * inv, e[6] * inv, e[7] * inv);
  *(float4*)&o[512] = make_float4(e[8] * inv, e[9] * inv, e[10] * inv, e[11] * inv);
  *(float4*)&o[516] = make_float4(e[12] * inv, e[13] * inv, e[14] * inv, e[15] * inv);
}

__global__ __launch_bounds__(256) void final32_k(float* __restrict__ Kb,
                                                 const float* __restrict__ Vp) {
  int gw   = (blockIdx.x * blockDim.x + threadIdx.x) >> 6;
  int lane = threadIdx.x & 63;
  int b = gw >> 11;
  const float* vp = Vp + b * TV;
  float* row = Kb + (size_t)gw * TV;
  float e[16];
  float s = 0.f;
  #pragma unroll
  for (int q = 0; q < 4; q++) {
    float4 kv = *(const float4*)&row[q * 256 + lane * 4];
    float4 vv = *(const float4*)&vp[q * 256 + lane * 4];
    e[q*4+0] = exp2f(kv.x + vv.x); e[q*4+1] = exp2f(kv.y + vv.y);
    e[q*4+2] = exp2f(kv.z + vv.z); e[q*4+3] = exp2f(kv.w + vv.w);
    s += e[q*4+0] + e[q*4+1] + e[q*4+2] + e[q*4+3];
  }
  s = wave_sum(s);
  float inv = 1.0f / s;
  #pragma unroll
  for (int q = 0; q < 4; q++)
    *(float4*)&row[q * 256 + lane * 4] =
        make_float4(e[q*4+0] * inv, e[q*4+1] * inv, e[q*4+2] * inv, e[q*4+3] * inv);
}

extern "C" void kernel_launch(void* const* d_in, const int* in_sizes, int n_in,
                              void* d_out, int out_size, void* d_ws, size_t ws_size,
                              hipStream_t stream) {
  const float* audio   = (const float*)d_in[0];
  const float* video   = (const float*)d_in[1];
  const float* quality = (const float*)d_in[2];
  const float* lam_t   = (const float*)d_in[3];
  const float* lam_q   = (const float*)d_in[4];

  float* out = (float*)d_out;
  float* ws  = (float*)d_ws;
  float* inv_na = ws;                         // 32768
  float* inv_nv = ws + 32768;                 // 16384
  float* Vp     = ws + 49152;                 // 16384
  float* pc     = ws + 65536;                 // 524288
  _Float16* Kh  = (_Float16*)(ws + 589824);   // 16*2048*1024 halves = 64 MiB

  size_t need_f16 = 589824ull * 4 + (size_t)B_ * TA * TV * 2;

  norms_k<<<12288, 256, 0, stream>>>(audio, video, inv_na, inv_nv);
  vinit_k<<<64, 256, 0, stream>>>(quality, lam_q, Vp);

  if (ws_size >= need_f16) {
    cost_k<true><<<dim3(16, 8, 16), 256, 0, stream>>>(audio, video, inv_na, inv_nv,
                                                      lam_t, nullptr, Kh);
    for (int it = 0; it < NIT; it++) {
      iter16_k<<<512, 512, 0, stream>>>(Kh, Vp, pc);
      vcomb_k<<<64, 256, 0, stream>>>(pc, Vp);
    }
    final16_k<<<8192, 256, 0, stream>>>(Kh, Vp, out);
  } else {
    float* Kb = out;  // K lives in d_out, transformed in place by final32_k
    cost_k<false><<<dim3(16, 8, 16), 256, 0, stream>>>(audio, video, inv_na, inv_nv,
                                                       lam_t, Kb, nullptr);
    for (int it = 0; it < NIT; it++) {
      iter32_k<<<512, 512, 0, stream>>>(Kb, Vp, pc);
      vcomb_k<<<64, 256, 0, stream>>>(pc, Vp);
    }
    final32_k<<<8192, 256, 0, stream>>>(Kb, Vp);
  }
}